// Round 5
// baseline (9586.456 us; speedup 1.0000x reference)
//
#include <hip/hip_runtime.h>
#include <math.h>

#define DEV __device__ __forceinline__

DEV float sigmoid_(float x) { return 1.0f / (1.0f + __expf(-x)); }
DEV float tanh_(float x) {
    float e = __expf(2.0f * x);
    return 1.0f - 2.0f / (e + 1.0f);
}

// ---------------------------------------------------------------------------
// zx_k: precompute z_x = bias + conv3x3(x_t) for a chunk of timesteps.
// Block = (b, tc, oc-group, spatial chunk); oc uniform per block -> weight
// loads are scalar (s_load, free on VALU). Each thread: RPT rows, OCL output
// channels, all 4 gates. Per ic: (RPT+2)*3 loads + masks feed OCL*4*9*RPT FMA.
// zx layout: [B,TcMax,4,hid,H,W]
// ---------------------------------------------------------------------------
template<int TPB, int OCL, int RPT>
__global__ __launch_bounds__(TPB) void zx_k(
    const float* __restrict__ xin,   // [B,T,Cin,H,W]
    const float* __restrict__ w,     // [4*hid, Ctot, 3, 3]
    const float* __restrict__ bias,  // [4*hid]
    float* __restrict__ zx,
    int t0, int TcAct, int TcMax, int B, int T, int Cin, int Ctot,
    int hid, int H, int W, int nOcg, int BPP)
{
    const int HW = H * W;
    int blk   = blockIdx.x;
    int chunk = blk % BPP;
    int ocg   = (blk / BPP) % nOcg;
    int tc    = (blk / (BPP * nOcg)) % TcAct;
    int b     = blk / (BPP * nOcg * TcAct);
    int oc0   = ocg * OCL;           // blockIdx-derived -> wave-uniform

    int p    = threadIdx.x;
    int col  = p % W;
    int rowg = p / W;
    int rpc  = (TPB / W) * RPT;      // rows per chunk
    int y0   = chunk * rpc + rowg * RPT;

    int   off[RPT + 2][3];
    float msk[RPT + 2][3];
    #pragma unroll
    for (int dy = 0; dy < RPT + 2; ++dy) {
        int yy = y0 + dy - 1;
        #pragma unroll
        for (int dx = 0; dx < 3; ++dx) {
            int xx = col + dx - 1;
            bool ok = (yy >= 0 && yy < H && xx >= 0 && xx < W);
            off[dy][dx] = ok ? yy * W + xx : 0;
            msk[dy][dx] = ok ? 1.0f : 0.0f;
        }
    }

    float z[RPT][OCL][4];
    #pragma unroll
    for (int r = 0; r < RPT; ++r)
        #pragma unroll
        for (int j = 0; j < OCL; ++j)
            #pragma unroll
            for (int g = 0; g < 4; ++g)
                z[r][j][g] = bias[g * hid + oc0 + j];

    const float* xsl = xin + ((size_t)(b * T + t0 + tc) * Cin) * HW;
    for (int ic = 0; ic < Cin; ++ic) {
        const float* src = xsl + (size_t)ic * HW;
        float v[RPT + 2][3];
        #pragma unroll
        for (int dy = 0; dy < RPT + 2; ++dy)
            #pragma unroll
            for (int dx = 0; dx < 3; ++dx)
                v[dy][dx] = src[off[dy][dx]] * msk[dy][dx];

        #pragma unroll
        for (int j = 0; j < OCL; ++j) {
            #pragma unroll
            for (int g = 0; g < 4; ++g) {
                const float* wp = w + ((size_t)(g * hid + oc0 + j) * Ctot + ic) * 9;
                #pragma unroll
                for (int k = 0; k < 9; ++k) {
                    float wv = wp[k];     // uniform addr -> s_load
                    #pragma unroll
                    for (int r = 0; r < RPT; ++r)
                        z[r][j][g] = fmaf(v[r + k / 3][k % 3], wv, z[r][j][g]);
                }
            }
        }
    }

    size_t base = ((size_t)(b * TcMax + tc) * 4 * hid) * HW;
    #pragma unroll
    for (int r = 0; r < RPT; ++r) {
        size_t rb = base + (size_t)(y0 + r) * W + col;
        #pragma unroll
        for (int j = 0; j < OCL; ++j)
            #pragma unroll
            for (int g = 0; g < 4; ++g)
                zx[rb + (size_t)(g * hid + oc0 + j) * HW] = z[r][j][g];
    }
}

// ---------------------------------------------------------------------------
// step_k: one ConvLSTM timestep. z = zx(precomputed) + conv3x3(h_{t-1});
// gates; state update. Same uniform-oc / register-blocked structure.
// ---------------------------------------------------------------------------
template<int TPB, int OCL, int RPT>
__global__ __launch_bounds__(TPB) void step_k(
    const float* __restrict__ zx,    // [B,TcMax,4,hid,H,W]
    const float* __restrict__ w,     // [4*hid, Ctot, 3, 3]
    float* __restrict__ hbuf,        // [B,T,hid,H,W]
    float* __restrict__ cbuf,        // [B,hid,H,W]
    int t, int tc, int TcMax, int B, int T, int Cin, int hid, int H, int W,
    int nOcg, int BPP)
{
    const int HW = H * W;
    const int Ctot = Cin + hid;
    int blk   = blockIdx.x;
    int chunk = blk % BPP;
    int ocg   = (blk / BPP) % nOcg;
    int b     = blk / (BPP * nOcg);
    int oc0   = ocg * OCL;

    int p    = threadIdx.x;
    int col  = p % W;
    int rowg = p / W;
    int rpc  = (TPB / W) * RPT;
    int y0   = chunk * rpc + rowg * RPT;

    int   off[RPT + 2][3];
    float msk[RPT + 2][3];
    #pragma unroll
    for (int dy = 0; dy < RPT + 2; ++dy) {
        int yy = y0 + dy - 1;
        #pragma unroll
        for (int dx = 0; dx < 3; ++dx) {
            int xx = col + dx - 1;
            bool ok = (yy >= 0 && yy < H && xx >= 0 && xx < W);
            off[dy][dx] = ok ? yy * W + xx : 0;
            msk[dy][dx] = ok ? 1.0f : 0.0f;
        }
    }

    float z[RPT][OCL][4];
    size_t zbase = ((size_t)(b * TcMax + tc) * 4 * hid) * HW;
    #pragma unroll
    for (int r = 0; r < RPT; ++r) {
        size_t rb = zbase + (size_t)(y0 + r) * W + col;
        #pragma unroll
        for (int j = 0; j < OCL; ++j)
            #pragma unroll
            for (int g = 0; g < 4; ++g)
                z[r][j][g] = zx[rb + (size_t)(g * hid + oc0 + j) * HW];
    }

    if (t > 0) {
        const float* hsl = hbuf + ((size_t)(b * T + (t - 1)) * hid) * HW;
        for (int ic = 0; ic < hid; ++ic) {
            const float* src = hsl + (size_t)ic * HW;
            float v[RPT + 2][3];
            #pragma unroll
            for (int dy = 0; dy < RPT + 2; ++dy)
                #pragma unroll
                for (int dx = 0; dx < 3; ++dx)
                    v[dy][dx] = src[off[dy][dx]] * msk[dy][dx];

            #pragma unroll
            for (int j = 0; j < OCL; ++j) {
                #pragma unroll
                for (int g = 0; g < 4; ++g) {
                    const float* wp = w + ((size_t)(g * hid + oc0 + j) * Ctot + Cin + ic) * 9;
                    #pragma unroll
                    for (int k = 0; k < 9; ++k) {
                        float wv = wp[k];
                        #pragma unroll
                        for (int r = 0; r < RPT; ++r)
                            z[r][j][g] = fmaf(v[r + k / 3][k % 3], wv, z[r][j][g]);
                    }
                }
            }
        }
    }

    #pragma unroll
    for (int r = 0; r < RPT; ++r) {
        int y = y0 + r;
        #pragma unroll
        for (int j = 0; j < OCL; ++j) {
            int oc = oc0 + j;
            size_t ci = ((size_t)b * hid + oc) * HW + (size_t)y * W + col;
            float cprev = (t == 0) ? 0.0f : cbuf[ci];
            float ig = sigmoid_(z[r][j][0]);
            float fg = sigmoid_(z[r][j][1]);
            float og = sigmoid_(z[r][j][2]);
            float gg = tanh_(z[r][j][3]);
            float cn = fg * cprev + ig * gg;
            cbuf[ci] = cn;
            hbuf[((size_t)(b * T + t) * hid + oc) * HW + (size_t)y * W + col] = og * tanh_(cn);
        }
    }
}

// ---------------------------------------------------------------------------
// BatchNorm stats / BN+ReLU+Pool / FC head
// ---------------------------------------------------------------------------
__global__ void bn_stats(const float* __restrict__ hbuf, float* __restrict__ stats,
                         int BT, int C, int HW)
{
    int c = blockIdx.x;
    float s = 0.0f, s2 = 0.0f;
    for (int bt = blockIdx.y; bt < BT; bt += gridDim.y) {
        const float* p = hbuf + ((size_t)bt * C + c) * HW;
        for (int i = threadIdx.x; i < HW; i += blockDim.x) {
            float v = p[i];
            s += v;
            s2 += v * v;
        }
    }
    __shared__ float ssum[256];
    __shared__ float ssq[256];
    int tid = threadIdx.x;
    ssum[tid] = s; ssq[tid] = s2;
    __syncthreads();
    for (int off = 128; off > 0; off >>= 1) {
        if (tid < off) { ssum[tid] += ssum[tid + off]; ssq[tid] += ssq[tid + off]; }
        __syncthreads();
    }
    if (tid == 0) {
        atomicAdd(&stats[2 * c + 0], ssum[0]);
        atomicAdd(&stats[2 * c + 1], ssq[0]);
    }
}

__global__ void bn_relu_pool(const float* __restrict__ hbuf,
                             const float* __restrict__ stats,
                             const float* __restrict__ gamma,
                             const float* __restrict__ beta,
                             float* __restrict__ out,
                             int BT, int C, int H, int W, float invN)
{
    int Ho = H / 2, Wo = W / 2;
    int idx = blockIdx.x * blockDim.x + threadIdx.x;
    int total = BT * C * Ho * Wo;
    if (idx >= total) return;
    int xo = idx % Wo;
    int yo = (idx / Wo) % Ho;
    int c  = (idx / (Wo * Ho)) % C;
    int bt = idx / (C * Ho * Wo);

    float mean = stats[2 * c + 0] * invN;
    float var  = stats[2 * c + 1] * invN - mean * mean;
    float sc = gamma[c] * rsqrtf(var + 1e-5f);
    float sh = beta[c] - mean * sc;

    const float* p = hbuf + ((size_t)bt * C + c) * (H * W) + (2 * yo) * W + 2 * xo;
    float a0 = fmaxf(fmaf(p[0],     sc, sh), 0.0f);
    float a1 = fmaxf(fmaf(p[1],     sc, sh), 0.0f);
    float a2 = fmaxf(fmaf(p[W],     sc, sh), 0.0f);
    float a3 = fmaxf(fmaf(p[W + 1], sc, sh), 0.0f);
    out[idx] = fmaxf(fmaxf(a0, a1), fmaxf(a2, a3));
}

__global__ __launch_bounds__(128) void fc_head(const float* __restrict__ feat,
                                               const float* __restrict__ fc1w,
                                               const float* __restrict__ fc1b,
                                               const float* __restrict__ fc2w,
                                               const float* __restrict__ fc2b,
                                               float* __restrict__ out)
{
    __shared__ float sf[1024];
    __shared__ float y1[128];
    int bt = blockIdx.x;
    const float* f = feat + (size_t)bt * 1024;
    for (int i = threadIdx.x; i < 1024; i += 128) sf[i] = f[i];
    __syncthreads();
    int k = threadIdx.x;
    float acc = fc1b[k];
    const float* wk = fc1w + (size_t)k * 1024;
    for (int d = 0; d < 1024; ++d) acc = fmaf(sf[d], wk[d], acc);
    y1[k] = fmaxf(acc, 0.0f);
    __syncthreads();
    if (k < 2) {
        float a = fc2b[k];
        const float* w2 = fc2w + k * 128;
        for (int j = 0; j < 128; ++j) a = fmaf(y1[j], w2[j], a);
        out[(size_t)bt * 2 + k] = a;
    }
}

// ---------------------------------------------------------------------------
// Host
// ---------------------------------------------------------------------------
static void launch_zx(int l, const float* in, const float* w, const float* bias,
                      float* zbuf, int t0, int TcAct, int TcMax, int B, int T,
                      int Cin, int hid, int H, int W, hipStream_t s)
{
    int Ctot = Cin + hid, HW = H * W;
    switch (l) {
        case 0: { const int TPB=256,OCL=4,RPT=2; int nOcg=hid/OCL, BPP=HW/(TPB*RPT);
            zx_k<256,4,2><<<B*TcAct*nOcg*BPP, TPB, 0, s>>>(in,w,bias,zbuf,t0,TcAct,TcMax,B,T,Cin,Ctot,hid,H,W,nOcg,BPP); } break;
        case 1: { const int TPB=256,OCL=4,RPT=2; int nOcg=hid/OCL, BPP=HW/(TPB*RPT);
            zx_k<256,4,2><<<B*TcAct*nOcg*BPP, TPB, 0, s>>>(in,w,bias,zbuf,t0,TcAct,TcMax,B,T,Cin,Ctot,hid,H,W,nOcg,BPP); } break;
        case 2: { const int TPB=256,OCL=4,RPT=1; int nOcg=hid/OCL, BPP=HW/(TPB*RPT);
            zx_k<256,4,1><<<B*TcAct*nOcg*BPP, TPB, 0, s>>>(in,w,bias,zbuf,t0,TcAct,TcMax,B,T,Cin,Ctot,hid,H,W,nOcg,BPP); } break;
        case 3: { const int TPB=64,OCL=4,RPT=1; int nOcg=hid/OCL, BPP=HW/(TPB*RPT);
            zx_k<64,4,1><<<B*TcAct*nOcg*BPP, TPB, 0, s>>>(in,w,bias,zbuf,t0,TcAct,TcMax,B,T,Cin,Ctot,hid,H,W,nOcg,BPP); } break;
    }
}

static void launch_step(int l, const float* zbuf, const float* w,
                        float* hbuf, float* cbuf, int t, int tc, int TcMax,
                        int B, int T, int Cin, int hid, int H, int W, hipStream_t s)
{
    int HW = H * W;
    switch (l) {
        case 0: { const int TPB=256,OCL=2,RPT=2; int nOcg=hid/OCL, BPP=HW/(TPB*RPT);
            step_k<256,2,2><<<B*nOcg*BPP, TPB, 0, s>>>(zbuf,w,hbuf,cbuf,t,tc,TcMax,B,T,Cin,hid,H,W,nOcg,BPP); } break;
        case 1: { const int TPB=256,OCL=2,RPT=2; int nOcg=hid/OCL, BPP=HW/(TPB*RPT);
            step_k<256,2,2><<<B*nOcg*BPP, TPB, 0, s>>>(zbuf,w,hbuf,cbuf,t,tc,TcMax,B,T,Cin,hid,H,W,nOcg,BPP); } break;
        case 2: { const int TPB=256,OCL=2,RPT=1; int nOcg=hid/OCL, BPP=HW/(TPB*RPT);
            step_k<256,2,1><<<B*nOcg*BPP, TPB, 0, s>>>(zbuf,w,hbuf,cbuf,t,tc,TcMax,B,T,Cin,hid,H,W,nOcg,BPP); } break;
        case 3: { const int TPB=64,OCL=2,RPT=1; int nOcg=hid/OCL, BPP=HW/(TPB*RPT);
            step_k<64,2,1><<<B*nOcg*BPP, TPB, 0, s>>>(zbuf,w,hbuf,cbuf,t,tc,TcMax,B,T,Cin,hid,H,W,nOcg,BPP); } break;
    }
}

extern "C" void kernel_launch(void* const* d_in, const int* in_sizes, int n_in,
                              void* d_out, int out_size, void* d_ws, size_t ws_size,
                              hipStream_t stream)
{
    const int B = 8, T = 40;
    const float* x = (const float*)d_in[0];

    // workspace layout (floats); total ~141 MB (proven available in round 3)
    float* hbuf  = (float*)d_ws;                 // 20,971,520
    float* pbuf  = hbuf + (size_t)20971520;      //  5,242,880
    float* cbuf  = pbuf + (size_t)5242880;       //    524,288
    float* stats = cbuf + (size_t)524288;        //        128
    float* zbuf  = stats + 128;                  //  8,388,608

    struct LCfg { int Cin, hid, H, W, Tc; };
    const LCfg L[4] = { {1, 16, 64, 64, 4}, {16, 32, 32, 32, 8},
                        {32, 64, 16, 16, 16}, {64, 64, 8, 8, 40} };

    const float* in = x;
    for (int l = 0; l < 4; ++l) {
        const float* w     = (const float*)d_in[1 + 4 * l];
        const float* bias  = (const float*)d_in[2 + 4 * l];
        const float* gamma = (const float*)d_in[3 + 4 * l];
        const float* beta  = (const float*)d_in[4 + 4 * l];
        const int Cin = L[l].Cin, hid = L[l].hid, H = L[l].H, W = L[l].W;
        const int HW = H * W;
        const int TcMax = L[l].Tc;

        for (int t0 = 0; t0 < T; t0 += TcMax) {
            int TcAct = (T - t0 < TcMax) ? (T - t0) : TcMax;
            launch_zx(l, in, w, bias, zbuf, t0, TcAct, TcMax, B, T, Cin, hid, H, W, stream);
            for (int t = t0; t < t0 + TcAct; ++t)
                launch_step(l, zbuf, w, hbuf, cbuf, t, t - t0, TcMax,
                            B, T, Cin, hid, H, W, stream);
        }

        hipMemsetAsync(stats, 0, 2 * hid * sizeof(float), stream);
        bn_stats<<<dim3(hid, 80), 256, 0, stream>>>(hbuf, stats, B * T, hid, HW);

        int ptotal = B * T * hid * (H / 2) * (W / 2);
        float invN = 1.0f / ((float)(B * T) * (float)HW);
        bn_relu_pool<<<(ptotal + 255) / 256, 256, 0, stream>>>(
            hbuf, stats, gamma, beta, pbuf, B * T, hid, H, W, invN);
        in = pbuf;
    }

    const float* fc1w = (const float*)d_in[17];
    const float* fc1b = (const float*)d_in[18];
    const float* fc2w = (const float*)d_in[19];
    const float* fc2b = (const float*)d_in[20];
    fc_head<<<B * T, 128, 0, stream>>>(pbuf, fc1w, fc1b, fc2w, fc2b, (float*)d_out);
}